// Round 5
// baseline (680.650 us; speedup 1.0000x reference)
//
#include <hip/hip_runtime.h>
#include <hip/hip_bf16.h>
#include <math.h>

#define Hh 4
#define Bb 32
#define Tt 1000
#define TP 1024
#define EPROJS_ 1024
#define DUNITS_ 1024
#define DKd 512
#define DVd 512
#define CC 100
#define KPAD 256
#define SCALING 0.04419417382415922f  // 1/sqrt(512)

typedef __attribute__((ext_vector_type(8))) short short8;
typedef __attribute__((ext_vector_type(4))) float floatx4;

__device__ __forceinline__ void async16(const void* g, void* l) {
    __builtin_amdgcn_global_load_lds(
        (const __attribute__((address_space(1))) unsigned int*)g,
        (__attribute__((address_space(3))) unsigned int*)l, 16, 0, 0);
}

__device__ __forceinline__ float fast_tanh(float x) {
    float xc = fminf(fmaxf(x, -9.f), 9.f);
    float p = __expf(2.f * xc);
    return (p - 1.f) * __builtin_amdgcn_rcpf(p + 1.f);
}

// ============ prep: enc->bf16 | Wk transpose->bf16 | conv*Watt->WWt | im2col A2
// grid ranges: [0,2048) enc_cvt, [2048,2560) wkt, [2560,3584) ww, [3584,4608) att2
__global__ __launch_bounds__(256) void prep_kernel(
    const float* __restrict__ enc, const float* __restrict__ Wk,
    const float* __restrict__ w0, const float* __restrict__ w1,
    const float* __restrict__ w2, const float* __restrict__ w3,
    const float* __restrict__ Watt, const float* __restrict__ att_prev,
    unsigned short* __restrict__ enc16, unsigned short* __restrict__ Wkt,
    __hip_bfloat16* __restrict__ WWt, unsigned short* __restrict__ att2)
{
    __shared__ __align__(16) float smem[4160];
    const int l = blockIdx.x;
    const int tid = threadIdx.x;

    if (l < 2048) {
        // ---- enc16[b][t][d] = bf16(enc[b][t][d]) ----
        int gtid = l * 256 + tid;
        for (int i = gtid; i < 8192000; i += 524288) {
            int b = i / 256000;
            int rem = i - b * 256000;
            int t = rem >> 8, d4 = rem & 255;
            float4 v = *(const float4*)(enc + ((size_t)(b * Tt + t)) * EPROJS_ + d4 * 4);
            union { __hip_bfloat162 h2[2]; uint2 u; } u;
            u.h2[0] = __float22bfloat162_rn(make_float2(v.x, v.y));
            u.h2[1] = __float22bfloat162_rn(make_float2(v.z, v.w));
            *(uint2*)(enc16 + ((size_t)(b * TP + t)) * EPROJS_ + d4 * 4) = u.u;
        }
    } else if (l < 2560) {
        // ---- Wkt[h][e][d] = bf16(Wk[h][d][e]) ----
        int l2 = l - 2048;
        int et = l2 & 7, dt = (l2 >> 3) & 15, h = l2 >> 7;
        float (*tile)[65] = (float(*)[65])smem;
        int r = tid >> 4, c4 = tid & 15;
        const float* src = Wk + ((size_t)(h * DUNITS_ + dt * 64)) * DKd + et * 64;
#pragma unroll
        for (int rr = 0; rr < 4; ++rr) {
            int row = r + rr * 16;
            *(float4*)&tile[row][c4 * 4] = *(const float4*)(src + (size_t)row * DKd + c4 * 4);
        }
        __syncthreads();
        unsigned short* dst = Wkt + ((size_t)(h * DKd + et * 64)) * EPROJS_ + dt * 64;
#pragma unroll
        for (int rr = 0; rr < 4; ++rr) {
            int el = r + rr * 16;
            union { __hip_bfloat162 h2[2]; uint2 u; } u;
            u.h2[0] = __float22bfloat162_rn(make_float2(tile[c4 * 4 + 0][el], tile[c4 * 4 + 1][el]));
            u.h2[1] = __float22bfloat162_rn(make_float2(tile[c4 * 4 + 2][el], tile[c4 * 4 + 3][el]));
            *(uint2*)(dst + (size_t)el * EPROJS_ + c4 * 4) = u.u;
        }
    } else if (l < 3584) {
        // ---- WWt[h][e][k], k zero-padded to 256 ----
        int l3 = l - 2560;
        int k = l3 & 255, h = l3 >> 8;
        int f = 25 * (h + 1), Kh = 2 * f + 1;
        const float* cw = (h == 0) ? w0 : (h == 1) ? w1 : (h == 2) ? w2 : w3;
        int e = tid;
        float acc0 = 0.f, acc1 = 0.f;
        if (k < Kh) {
            for (int c = 0; c < CC; ++c) {
                float wv = cw[c * Kh + k];
                acc0 += wv * Watt[(h * CC + c) * DKd + e];
                acc1 += wv * Watt[(h * CC + c) * DKd + e + 256];
            }
        }
        WWt[((size_t)(h * DKd + e)) * KPAD + k] = __float2bfloat16(acc0);
        WWt[((size_t)(h * DKd + e + 256)) * KPAD + k] = __float2bfloat16(acc1);
    } else {
        // ---- att2[h][b][by][r][k] = bf16(att_prev[h,b, by*128+r-f+k]) ----
        int l4 = l - 3584;
        int h = l4 >> 8, b = (l4 >> 3) & 31, by = l4 & 7;
        int f = 25 * (h + 1);
        int Kpad = 64 * (h + 1);
        int t0 = by * 128;
        const float* ab = att_prev + (size_t)(h * Bb + b) * Tt;
        float* win = smem;
        int winlen = 127 + Kpad;
        for (int i = tid; i < winlen; i += 256) {
            int s = t0 - f + i;
            win[i] = (s >= 0 && s < Tt) ? ab[s] : 0.f;
        }
        __syncthreads();
        int a2off = 2097152 * ((h * (h + 1)) >> 1);
        int r = tid >> 1, half = tid & 1;
        unsigned short* dst = att2 + a2off + (size_t)(((b * 8 + by) * 128) + r) * Kpad;
        int nst = Kpad >> 4;   // short8 stores per thread
        for (int j = 0; j < nst; ++j) {
            int k = half * (Kpad >> 1) + j * 8;
            union { short8 s; __hip_bfloat162 hh[4]; } u;
#pragma unroll
            for (int q2 = 0; q2 < 4; ++q2)
                u.hh[q2] = __float22bfloat162_rn(
                    make_float2(win[r + k + 2 * q2], win[r + k + 2 * q2 + 1]));
            *(short8*)(dst + k) = u.s;
        }
    }
}

// ---------------- q[h,b,e] = dec_z[b,:] . Wq[h,:,e] (broadcast GEMM) ----------
__global__ __launch_bounds__(256) void q_kernel(
    const float* __restrict__ dec_z, const float* __restrict__ Wq,
    float* __restrict__ q_buf)
{
    int col = blockIdx.x * 8 + (threadIdx.x & 7);   // 0..2047 = h*512+e
    int b = threadIdx.x >> 3;
    int h = col >> 9, e = col & 511;
    const float* zp = dec_z + (size_t)b * DUNITS_;
    const float* wp = Wq + (size_t)h * DUNITS_ * DKd + e;
    float acc = 0.f;
#pragma unroll 16
    for (int k = 0; k < DUNITS_; ++k)
        acc += zp[k] * wp[(size_t)k * DKd];
    q_buf[(h * Bb + b) * DKd + e] = acc;
}

// ---------------- e[h,b,t]: MFMA bf16 GEMM + fused tanh-dot epilogue -----------
__global__ __launch_bounds__(256) void e_kernel(
    const unsigned short* __restrict__ enc16, const unsigned short* __restrict__ Wkt,
    const unsigned short* __restrict__ att2, const __hip_bfloat16* __restrict__ WWt,
    const float* __restrict__ q_buf, const float* __restrict__ bq,
    const float* __restrict__ g_w, float* __restrict__ e_buf)
{
    const int lin = blockIdx.x;
    const int xcd = lin & 7, pos = lin >> 3;
    const int b = (pos >> 7) * 8 + xcd;
    const int rem = pos & 127;
    const int h = rem >> 5;
    const int by = (rem & 31) >> 2;
    const int bx = rem & 3;
    const int t0 = by * 128, e0 = bx * 128;
    const int tid = threadIdx.x;
    const int lane = tid & 63, w = tid >> 6;
    const int wr = w >> 1, wc = w & 1;
    const int m = lane & 15, quad = lane >> 4;
    const int srow = tid >> 3;
    const int ko = (((tid & 7) ^ (srow & 7))) * 8;   // swizzled source k-offset
    const int sw = m & 7;                             // fragment-read swizzle

    __shared__ __align__(16) short As[128 * 64];
    __shared__ __align__(16) short Bs[128 * 64];

    floatx4 acc[4][4];
#pragma unroll
    for (int i = 0; i < 4; ++i)
#pragma unroll
        for (int j = 0; j < 4; ++j) acc[i][j] = (floatx4){0.f, 0.f, 0.f, 0.f};

    const unsigned short* WkB = Wkt + ((size_t)(h * DKd + e0)) * EPROJS_;
    const unsigned short* encB = enc16 + ((size_t)(b * TP + t0)) * EPROJS_;
    char* AsDst = (char*)As + (tid & ~63) * 16;
    char* BsDst = (char*)Bs + (tid & ~63) * 16;

    // ---- phase 1: K=1024 over d, BK=64 ----
    for (int ch = 0; ch < 16; ++ch) {
        int d0 = ch * 64;
        __syncthreads();
#pragma unroll
        for (int it = 0; it < 4; ++it) {
            int r2 = it * 32 + srow;
            async16(encB + (size_t)r2 * EPROJS_ + d0 + ko, AsDst + it * 4096);
            async16(WkB + (size_t)r2 * EPROJS_ + d0 + ko, BsDst + it * 4096);
        }
        __syncthreads();
#pragma unroll
        for (int ks = 0; ks < 2; ++ks) {
            short8 af[4], bf[4];
#pragma unroll
            for (int i = 0; i < 4; ++i)
                af[i] = *(const short8*)&As[(wr * 64 + i * 16 + m) * 64 + (((ks << 2) + quad) ^ sw) * 8];
#pragma unroll
            for (int j = 0; j < 4; ++j)
                bf[j] = *(const short8*)&Bs[(wc * 64 + j * 16 + m) * 64 + (((ks << 2) + quad) ^ sw) * 8];
#pragma unroll
            for (int i = 0; i < 4; ++i)
#pragma unroll
                for (int j = 0; j < 4; ++j)
                    acc[i][j] = __builtin_amdgcn_mfma_f32_16x16x32_bf16(
                        af[i], bf[j], acc[i][j], 0, 0, 0);
        }
    }

    // ---- phase 2: banded location term via materialized A2, BK=64, pure async -
    const int Kpad = 64 * (h + 1);
    const int a2off = 2097152 * ((h * (h + 1)) >> 1);
    const unsigned short* A2B = att2 + a2off + (size_t)((b * 8 + by) * 128) * Kpad;
    const __hip_bfloat16* WWB = WWt + ((size_t)(h * DKd + e0)) * KPAD;
    for (int ch = 0; ch <= h; ++ch) {
        int k0 = ch * 64;
        __syncthreads();
#pragma unroll
        for (int it = 0; it < 4; ++it) {
            int r2 = it * 32 + srow;
            async16(A2B + (size_t)r2 * Kpad + k0 + ko, AsDst + it * 4096);
            async16(WWB + (size_t)r2 * KPAD + k0 + ko, BsDst + it * 4096);
        }
        __syncthreads();
#pragma unroll
        for (int ks = 0; ks < 2; ++ks) {
            short8 af[4], bf[4];
#pragma unroll
            for (int i = 0; i < 4; ++i)
                af[i] = *(const short8*)&As[(wr * 64 + i * 16 + m) * 64 + (((ks << 2) + quad) ^ sw) * 8];
#pragma unroll
            for (int j = 0; j < 4; ++j)
                bf[j] = *(const short8*)&Bs[(wc * 64 + j * 16 + m) * 64 + (((ks << 2) + quad) ^ sw) * 8];
#pragma unroll
            for (int i = 0; i < 4; ++i)
#pragma unroll
                for (int j = 0; j < 4; ++j)
                    acc[i][j] = __builtin_amdgcn_mfma_f32_16x16x32_bf16(
                        af[i], bf[j], acc[i][j], 0, 0, 0);
        }
    }

    // ---- epilogue ----
    const float* qrow = q_buf + (size_t)(h * Bb + b) * DKd;
    const float* bqrow = bq + h * DKd;
    const float* gwrow = g_w + h * DKd;
    float qv[4], gw[4];
#pragma unroll
    for (int j = 0; j < 4; ++j) {
        int e = e0 + wc * 64 + j * 16 + m;
        qv[j] = qrow[e] + bqrow[e];
        gw[j] = gwrow[e];
    }
    float* erow = e_buf + (size_t)(h * Bb + b) * Tt;
#pragma unroll
    for (int i = 0; i < 4; ++i) {
#pragma unroll
        for (int reg = 0; reg < 4; ++reg) {
            float s = 0.f;
#pragma unroll
            for (int j = 0; j < 4; ++j)
                s += fast_tanh(acc[i][j][reg] + qv[j]) * gw[j];
            s += __shfl_xor(s, 1);
            s += __shfl_xor(s, 2);
            s += __shfl_xor(s, 4);
            s += __shfl_xor(s, 8);
            int t = t0 + wr * 64 + i * 16 + quad * 4 + reg;
            if (m == 0 && t < Tt)
                atomicAdd(&erow[t], s);
        }
    }
}

// ---------------- w = softmax(scaling * e) over T ------------------------------
__global__ __launch_bounds__(256) void softmax_kernel(
    const float* __restrict__ e_buf, float* __restrict__ wout)
{
    int rowid = blockIdx.x;
    const float* x = e_buf + rowid * Tt;
    float* y = wout + rowid * Tt;
    int tid = threadIdx.x;
    float v[4];
    float mx = -1e30f;
#pragma unroll
    for (int k = 0; k < 4; ++k) {
        int t = tid + k * 256;
        v[k] = (t < Tt) ? x[t] * SCALING : -1e30f;
        mx = fmaxf(mx, v[k]);
    }
    for (int off = 32; off >= 1; off >>= 1) mx = fmaxf(mx, __shfl_xor(mx, off));
    __shared__ float sm[4];
    __shared__ float ss[4];
    int wave = tid >> 6;
    if ((tid & 63) == 0) sm[wave] = mx;
    __syncthreads();
    mx = fmaxf(fmaxf(sm[0], sm[1]), fmaxf(sm[2], sm[3]));
    float s = 0.f;
#pragma unroll
    for (int k = 0; k < 4; ++k) {
        int t = tid + k * 256;
        v[k] = (t < Tt) ? __expf(v[k] - mx) : 0.f;
        s += v[k];
    }
    for (int off = 32; off >= 1; off >>= 1) s += __shfl_xor(s, off);
    if ((tid & 63) == 0) ss[wave] = s;
    __syncthreads();
    s = ss[0] + ss[1] + ss[2] + ss[3];
    float inv = 1.0f / s;
#pragma unroll
    for (int k = 0; k < 4; ++k) {
        int t = tid + k * 256;
        if (t < Tt) y[t] = v[k] * inv;
    }
}

// ---------------- ctx[h,b,d] = sum_t w[h,b,t] * enc16[b,t,d] (direct write) ----
__global__ __launch_bounds__(256) void ctx_kernel(
    const float* __restrict__ wout, const unsigned short* __restrict__ enc16,
    float* __restrict__ ctx)
{
    int dch = blockIdx.x;    // 0..7
    int b = blockIdx.y;      // 0..31
    int tid = threadIdx.x;
    __shared__ float wl[4][1000];
    __shared__ float red[8 * 4 * 128];
    for (int i = tid; i < 4000; i += 256) {
        int h = i >> 10, tl = i & 1023;      // careful: 1000 not pow2
        h = i / 1000; tl = i - h * 1000;
        wl[h][tl] = wout[(h * Bb + b) * Tt + tl];
    }
    __syncthreads();
    int g = tid >> 5, c = tid & 31;
    int d0 = dch * 128;
    float4 a[4];
#pragma unroll
    for (int h = 0; h < 4; ++h) a[h] = make_float4(0.f, 0.f, 0.f, 0.f);
    const unsigned short* encB = enc16 + (size_t)b * TP * EPROJS_ + d0 + c * 4;
    for (int t = g; t < Tt; t += 8) {
        uint2 raw = *(const uint2*)(encB + (size_t)t * EPROJS_);
        float x0 = __uint_as_float(raw.x << 16);
        float x1 = __uint_as_float(raw.x & 0xffff0000u);
        float x2 = __uint_as_float(raw.y << 16);
        float x3 = __uint_as_float(raw.y & 0xffff0000u);
#pragma unroll
        for (int h = 0; h < 4; ++h) {
            float wv = wl[h][t];
            a[h].x += wv * x0; a[h].y += wv * x1;
            a[h].z += wv * x2; a[h].w += wv * x3;
        }
    }
#pragma unroll
    for (int h = 0; h < 4; ++h)
        *(float4*)&red[((g * 4 + h) << 7) + c * 4] = a[h];
    __syncthreads();
    for (int i = tid; i < 512; i += 256) {
        int h = i >> 7, dd = i & 127;
        float ssum = 0.f;
#pragma unroll
        for (int g2 = 0; g2 < 8; ++g2) ssum += red[((g2 * 4 + h) << 7) + dd];
        ctx[(h * Bb + b) * EPROJS_ + d0 + dd] = ssum;
    }
}

// ---------------- c[h,b,e] = ctx[h,b,:] . Wv[h,:,e] (broadcast GEMM) ----------
__global__ __launch_bounds__(256) void c_kernel(
    const float* __restrict__ ctx, const float* __restrict__ Wv,
    float* __restrict__ c_buf)
{
    int col = blockIdx.x * 8 + (threadIdx.x & 7);   // h*512+e
    int b = threadIdx.x >> 3;
    int h = col >> 9, e = col & 511;
    const float* xp = ctx + (size_t)(h * Bb + b) * EPROJS_;
    const float* wp = Wv + (size_t)h * EPROJS_ * DVd + e;
    float acc = 0.f;
#pragma unroll 16
    for (int k = 0; k < EPROJS_; ++k)
        acc += xp[k] * wp[(size_t)k * DVd];
    c_buf[(h * Bb + b) * DVd + e] = acc;
}

// ---------------- out[b,o] = c[b,:] . Wo[:,o] (broadcast GEMM) ----------------
__global__ __launch_bounds__(256) void out_kernel(
    const float* __restrict__ c_buf, const float* __restrict__ Wo,
    float* __restrict__ outp)
{
    int o = blockIdx.x * 8 + (threadIdx.x & 7);     // 0..1023
    int b = threadIdx.x >> 3;
    const float* cp = c_buf + (size_t)b * DVd;      // [h*32+b][e] view: h stride = 32*512
    const float* wp = Wo + o;
    float acc = 0.f;
#pragma unroll 16
    for (int k = 0; k < 2048; ++k) {
        int h = k >> 9, e = k & 511;
        acc += cp[(size_t)h * Bb * DVd + e] * wp[(size_t)k * EPROJS_];
    }
    outp[b * EPROJS_ + o] = acc;
}

extern "C" void kernel_launch(void* const* d_in, const int* in_sizes, int n_in,
                              void* d_out, int out_size, void* d_ws, size_t ws_size,
                              hipStream_t stream) {
    const float* enc     = (const float*)d_in[0];
    const float* dec_z   = (const float*)d_in[2];
    const float* att_prev= (const float*)d_in[3];
    const float* Wq      = (const float*)d_in[4];
    const float* bq      = (const float*)d_in[5];
    const float* Wk      = (const float*)d_in[6];
    const float* Wv      = (const float*)d_in[7];
    const float* g_w     = (const float*)d_in[8];
    const float* Watt    = (const float*)d_in[10];
    const float* Wo      = (const float*)d_in[11];
    const float* cw0     = (const float*)d_in[12];
    const float* cw1     = (const float*)d_in[13];
    const float* cw2     = (const float*)d_in[14];
    const float* cw3     = (const float*)d_in[15];

    float* ws    = (float*)d_ws;
    float* q_buf = ws;                          // 65536 f
    float* e_buf = ws + 65536;                  // 128000 f (zeroed)
    float* c_buf = ws + 193536;                 // 65536 f
    float* ctx   = ws + 259072;                 // 131072 f
    unsigned short* enc16 = (unsigned short*)(ws + 390144);   // 33,554,432 sh
    unsigned short* Wkt   = (unsigned short*)(ws + 17167360); // 2,097,152 sh
    __hip_bfloat16* WWt   = (__hip_bfloat16*)(ws + 18215936); // 524,288 sh
    unsigned short* att2  = (unsigned short*)(ws + 18478080); // 20,971,520 sh
    float* outp  = (float*)d_out;               // 32768 f
    float* wout  = outp + 32768;                // 128000 f

    // only e_buf is atomically accumulated
    hipMemsetAsync(e_buf, 0, (size_t)128000 * sizeof(float), stream);

    prep_kernel<<<4608, 256, 0, stream>>>(enc, Wk, cw0, cw1, cw2, cw3, Watt,
                                          att_prev, enc16, Wkt, WWt, att2);
    q_kernel<<<256, 256, 0, stream>>>(dec_z, Wq, q_buf);
    e_kernel<<<4096, 256, 0, stream>>>(enc16, Wkt, att2, WWt,
                                       q_buf, bq, g_w, e_buf);
    softmax_kernel<<<128, 256, 0, stream>>>(e_buf, wout);
    ctx_kernel<<<dim3(8, 32), 256, 0, stream>>>(wout, enc16, ctx);
    c_kernel<<<256, 256, 0, stream>>>(ctx, Wv, c_buf);
    out_kernel<<<128, 256, 0, stream>>>(c_buf, Wo, outp);
}

// Round 6
// 633.108 us; speedup vs baseline: 1.0751x; 1.0751x over previous
//
#include <hip/hip_runtime.h>
#include <hip/hip_bf16.h>
#include <math.h>

#define Hh 4
#define Bb 32
#define Tt 1000
#define TP 1024
#define EPROJS_ 1024
#define DUNITS_ 1024
#define DKd 512
#define DVd 512
#define CC 100
#define KPAD 256
#define SCALING 0.04419417382415922f  // 1/sqrt(512)

typedef __attribute__((ext_vector_type(8))) short short8;
typedef __attribute__((ext_vector_type(4))) float floatx4;

__device__ __forceinline__ void async16(const void* g, void* l) {
    __builtin_amdgcn_global_load_lds(
        (const __attribute__((address_space(1))) unsigned int*)g,
        (__attribute__((address_space(3))) unsigned int*)l, 16, 0, 0);
}

__device__ __forceinline__ float fast_tanh(float x) {
    float xc = fminf(fmaxf(x, -9.f), 9.f);
    float p = __expf(2.f * xc);
    return (p - 1.f) * __builtin_amdgcn_rcpf(p + 1.f);
}

// ===== prep: enc->bf16 | Wk^T->bf16 | conv*Watt->WWt | im2col A2 | q partials
// ranges: [0,2048) enc, [2048,2560) wkt, [2560,3584) ww, [3584,4608) att2,
//         [4608,4672) q
__global__ __launch_bounds__(256) void prep_kernel(
    const float* __restrict__ enc, const float* __restrict__ Wk,
    const float* __restrict__ w0, const float* __restrict__ w1,
    const float* __restrict__ w2, const float* __restrict__ w3,
    const float* __restrict__ Watt, const float* __restrict__ att_prev,
    const float* __restrict__ dec_z, const float* __restrict__ Wq,
    unsigned short* __restrict__ enc16, unsigned short* __restrict__ Wkt,
    __hip_bfloat16* __restrict__ WWt, unsigned short* __restrict__ att2,
    float* __restrict__ q_part)
{
    __shared__ __align__(16) float smem[8192];
    const int l = blockIdx.x;
    const int tid = threadIdx.x;

    if (l < 2048) {
        // ---- enc16[b][t][d] = bf16(enc[b][t][d]) ----
        int gtid = l * 256 + tid;
        for (int i = gtid; i < 8192000; i += 524288) {
            int b = i / 256000;
            int rem = i - b * 256000;
            int t = rem >> 8, d4 = rem & 255;
            float4 v = *(const float4*)(enc + ((size_t)(b * Tt + t)) * EPROJS_ + d4 * 4);
            union { __hip_bfloat162 h2[2]; uint2 u; } u;
            u.h2[0] = __float22bfloat162_rn(make_float2(v.x, v.y));
            u.h2[1] = __float22bfloat162_rn(make_float2(v.z, v.w));
            *(uint2*)(enc16 + ((size_t)(b * TP + t)) * EPROJS_ + d4 * 4) = u.u;
        }
    } else if (l < 2560) {
        // ---- Wkt[h][e][d] = bf16(Wk[h][d][e]) ----
        int l2 = l - 2048;
        int et = l2 & 7, dt = (l2 >> 3) & 15, h = l2 >> 7;
        float (*tile)[65] = (float(*)[65])smem;
        int r = tid >> 4, c4 = tid & 15;
        const float* src = Wk + ((size_t)(h * DUNITS_ + dt * 64)) * DKd + et * 64;
#pragma unroll
        for (int rr = 0; rr < 4; ++rr) {
            int row = r + rr * 16;
            *(float4*)&tile[row][c4 * 4] = *(const float4*)(src + (size_t)row * DKd + c4 * 4);
        }
        __syncthreads();
        unsigned short* dst = Wkt + ((size_t)(h * DKd + et * 64)) * EPROJS_ + dt * 64;
#pragma unroll
        for (int rr = 0; rr < 4; ++rr) {
            int el = r + rr * 16;
            union { __hip_bfloat162 h2[2]; uint2 u; } u;
            u.h2[0] = __float22bfloat162_rn(make_float2(tile[c4 * 4 + 0][el], tile[c4 * 4 + 1][el]));
            u.h2[1] = __float22bfloat162_rn(make_float2(tile[c4 * 4 + 2][el], tile[c4 * 4 + 3][el]));
            *(uint2*)(dst + (size_t)el * EPROJS_ + c4 * 4) = u.u;
        }
    } else if (l < 3584) {
        // ---- WWt[h][e][k], k zero-padded to 256 ----
        int l3 = l - 2560;
        int k = l3 & 255, h = l3 >> 8;
        int f = 25 * (h + 1), Kh = 2 * f + 1;
        const float* cw = (h == 0) ? w0 : (h == 1) ? w1 : (h == 2) ? w2 : w3;
        int e = tid;
        float acc0 = 0.f, acc1 = 0.f;
        if (k < Kh) {
            for (int c = 0; c < CC; ++c) {
                float wv = cw[c * Kh + k];
                acc0 += wv * Watt[(h * CC + c) * DKd + e];
                acc1 += wv * Watt[(h * CC + c) * DKd + e + 256];
            }
        }
        WWt[((size_t)(h * DKd + e)) * KPAD + k] = __float2bfloat16(acc0);
        WWt[((size_t)(h * DKd + e + 256)) * KPAD + k] = __float2bfloat16(acc1);
    } else if (l < 4608) {
        // ---- att2[h][b][by][r][k] = bf16(att_prev[h,b, by*128+r-f+k]) ----
        int l4 = l - 3584;
        int h = l4 >> 8, b = (l4 >> 3) & 31, by = l4 & 7;
        int f = 25 * (h + 1);
        int Kpad = 64 * (h + 1);
        int t0 = by * 128;
        const float* ab = att_prev + (size_t)(h * Bb + b) * Tt;
        float* win = smem;
        int winlen = 127 + Kpad;
        for (int i = tid; i < winlen; i += 256) {
            int s = t0 - f + i;
            win[i] = (s >= 0 && s < Tt) ? ab[s] : 0.f;
        }
        __syncthreads();
        int a2off = 2097152 * ((h * (h + 1)) >> 1);
        int r = tid >> 1, half = tid & 1;
        unsigned short* dst = att2 + a2off + (size_t)(((b * 8 + by) * 128) + r) * Kpad;
        int nst = Kpad >> 4;
        for (int j = 0; j < nst; ++j) {
            int k = half * (Kpad >> 1) + j * 8;
            union { short8 s; __hip_bfloat162 hh[4]; } u;
#pragma unroll
            for (int q2 = 0; q2 < 4; ++q2)
                u.hh[q2] = __float22bfloat162_rn(
                    make_float2(win[r + k + 2 * q2], win[r + k + 2 * q2 + 1]));
            *(short8*)(dst + k) = u.s;
        }
    } else {
        // ---- q partials: q_part[kc*2+half][h,b,e] over 128-k slice ----
        int l5 = l - 4608;
        int et = l5 & 3, kc = (l5 >> 2) & 3, h = l5 >> 4;
        int d0 = kc * 256;
        float* zs = smem;   // [32][256]
        {
            int bld = tid >> 3, dc = (tid & 7) * 32;
            const float* p = dec_z + (size_t)bld * DUNITS_ + d0 + dc;
#pragma unroll
            for (int j = 0; j < 8; ++j)
                *(float4*)&zs[bld * 256 + dc + j * 4] = *(const float4*)(p + j * 4);
        }
        __syncthreads();
        int e = et * 128 + (tid & 127);
        int half = tid >> 7;          // which 128-k half
        int kb = half * 128;
        float acc[32];
#pragma unroll
        for (int b = 0; b < 32; ++b) acc[b] = 0.f;
        for (int c32 = 0; c32 < 4; ++c32) {
            float wq[32];
#pragma unroll
            for (int dl = 0; dl < 32; ++dl)
                wq[dl] = Wq[((size_t)(h * DUNITS_ + d0 + kb + c32 * 32 + dl)) * DKd + e];
#pragma unroll
            for (int b = 0; b < 32; ++b) {
                float s = 0.f;
#pragma unroll
                for (int dl = 0; dl < 32; ++dl)
                    s += zs[b * 256 + kb + c32 * 32 + dl] * wq[dl];
                acc[b] += s;
            }
        }
        float* qp = q_part + (size_t)(kc * 2 + half) * 65536 + (h * Bb) * DKd + e;
#pragma unroll
        for (int b = 0; b < 32; ++b)
            qp[b * DKd] = acc[b];
    }
}

// ---------------- e[h,b,t]: MFMA bf16 GEMM + fused tanh-dot epilogue -----------
__global__ __launch_bounds__(256) void e_kernel(
    const unsigned short* __restrict__ enc16, const unsigned short* __restrict__ Wkt,
    const unsigned short* __restrict__ att2, const __hip_bfloat16* __restrict__ WWt,
    const float* __restrict__ q_part, const float* __restrict__ bq,
    const float* __restrict__ g_w, float* __restrict__ e_buf)
{
    const int lin = blockIdx.x;
    const int xcd = lin & 7, pos = lin >> 3;
    const int b = (pos >> 7) * 8 + xcd;
    const int rem = pos & 127;
    const int h = rem >> 5;
    const int by = (rem & 31) >> 2;
    const int bx = rem & 3;
    const int t0 = by * 128, e0 = bx * 128;
    const int tid = threadIdx.x;
    const int lane = tid & 63, w = tid >> 6;
    const int wr = w >> 1, wc = w & 1;
    const int m = lane & 15, quad = lane >> 4;
    const int srow = tid >> 3;
    const int ko = (((tid & 7) ^ (srow & 7))) * 8;
    const int sw = m & 7;

    __shared__ __align__(16) short As[128 * 64];
    __shared__ __align__(16) short Bs[128 * 64];

    floatx4 acc[4][4];
#pragma unroll
    for (int i = 0; i < 4; ++i)
#pragma unroll
        for (int j = 0; j < 4; ++j) acc[i][j] = (floatx4){0.f, 0.f, 0.f, 0.f};

    const unsigned short* WkB = Wkt + ((size_t)(h * DKd + e0)) * EPROJS_;
    const unsigned short* encB = enc16 + ((size_t)(b * TP + t0)) * EPROJS_;
    char* AsDst = (char*)As + (tid & ~63) * 16;
    char* BsDst = (char*)Bs + (tid & ~63) * 16;

    // ---- phase 1: K=1024 over d, BK=64 ----
    for (int ch = 0; ch < 16; ++ch) {
        int d0 = ch * 64;
        __syncthreads();
#pragma unroll
        for (int it = 0; it < 4; ++it) {
            int r2 = it * 32 + srow;
            async16(encB + (size_t)r2 * EPROJS_ + d0 + ko, AsDst + it * 4096);
            async16(WkB + (size_t)r2 * EPROJS_ + d0 + ko, BsDst + it * 4096);
        }
        __syncthreads();
#pragma unroll
        for (int ks = 0; ks < 2; ++ks) {
            short8 af[4], bf[4];
#pragma unroll
            for (int i = 0; i < 4; ++i)
                af[i] = *(const short8*)&As[(wr * 64 + i * 16 + m) * 64 + (((ks << 2) + quad) ^ sw) * 8];
#pragma unroll
            for (int j = 0; j < 4; ++j)
                bf[j] = *(const short8*)&Bs[(wc * 64 + j * 16 + m) * 64 + (((ks << 2) + quad) ^ sw) * 8];
#pragma unroll
            for (int i = 0; i < 4; ++i)
#pragma unroll
                for (int j = 0; j < 4; ++j)
                    acc[i][j] = __builtin_amdgcn_mfma_f32_16x16x32_bf16(
                        af[i], bf[j], acc[i][j], 0, 0, 0);
        }
    }

    // ---- phase 2: banded location term via materialized A2, BK=64 ----
    const int Kpad = 64 * (h + 1);
    const int a2off = 2097152 * ((h * (h + 1)) >> 1);
    const unsigned short* A2B = att2 + a2off + (size_t)((b * 8 + by) * 128) * Kpad;
    const __hip_bfloat16* WWB = WWt + ((size_t)(h * DKd + e0)) * KPAD;
    for (int ch = 0; ch <= h; ++ch) {
        int k0 = ch * 64;
        __syncthreads();
#pragma unroll
        for (int it = 0; it < 4; ++it) {
            int r2 = it * 32 + srow;
            async16(A2B + (size_t)r2 * Kpad + k0 + ko, AsDst + it * 4096);
            async16(WWB + (size_t)r2 * KPAD + k0 + ko, BsDst + it * 4096);
        }
        __syncthreads();
#pragma unroll
        for (int ks = 0; ks < 2; ++ks) {
            short8 af[4], bf[4];
#pragma unroll
            for (int i = 0; i < 4; ++i)
                af[i] = *(const short8*)&As[(wr * 64 + i * 16 + m) * 64 + (((ks << 2) + quad) ^ sw) * 8];
#pragma unroll
            for (int j = 0; j < 4; ++j)
                bf[j] = *(const short8*)&Bs[(wc * 64 + j * 16 + m) * 64 + (((ks << 2) + quad) ^ sw) * 8];
#pragma unroll
            for (int i = 0; i < 4; ++i)
#pragma unroll
                for (int j = 0; j < 4; ++j)
                    acc[i][j] = __builtin_amdgcn_mfma_f32_16x16x32_bf16(
                        af[i], bf[j], acc[i][j], 0, 0, 0);
        }
    }

    // ---- epilogue: sum q partials, +bq, tanh, *g_w, reduce, atomicAdd ---------
    const float* bqrow = bq + h * DKd;
    const float* gwrow = g_w + h * DKd;
    float qv[4], gw[4];
#pragma unroll
    for (int j = 0; j < 4; ++j) {
        int e = e0 + wc * 64 + j * 16 + m;
        size_t qi = (size_t)(h * Bb + b) * DKd + e;
        float s = bqrow[e];
#pragma unroll
        for (int pp = 0; pp < 8; ++pp)
            s += q_part[pp * 65536 + qi];
        qv[j] = s;
        gw[j] = gwrow[e];
    }
    float* erow = e_buf + (size_t)(h * Bb + b) * Tt;
#pragma unroll
    for (int i = 0; i < 4; ++i) {
#pragma unroll
        for (int reg = 0; reg < 4; ++reg) {
            float s = 0.f;
#pragma unroll
            for (int j = 0; j < 4; ++j)
                s += fast_tanh(acc[i][j][reg] + qv[j]) * gw[j];
            s += __shfl_xor(s, 1);
            s += __shfl_xor(s, 2);
            s += __shfl_xor(s, 4);
            s += __shfl_xor(s, 8);
            int t = t0 + wr * 64 + i * 16 + quad * 4 + reg;
            if (m == 0 && t < Tt)
                atomicAdd(&erow[t], s);
        }
    }
}

// ===== fused: softmax(e) -> w (written once) ; ctx slice in LDS ; c partial ====
// grid (8 dchunk, 32 b). Each block recomputes the cheap 4-row softmax.
__global__ __launch_bounds__(256) void smax_ctx_c_kernel(
    const float* __restrict__ e_buf, const unsigned short* __restrict__ enc16,
    const float* __restrict__ Wv, float* __restrict__ wout,
    float* __restrict__ c_buf)
{
    int dch = blockIdx.x;
    int b = blockIdx.y;
    int tid = threadIdx.x;
    __shared__ float wl[4][1000];
    __shared__ float red[8 * 4 * 128];
    __shared__ float ctxs[4][128];

    // ---- softmax: wave w handles h=w ----
    {
        int wv_ = tid >> 6, lane = tid & 63;
        const float* x = e_buf + (size_t)(wv_ * Bb + b) * Tt;
        float v[16];
        float mx = -1e30f;
#pragma unroll
        for (int k = 0; k < 16; ++k) {
            int t = k * 64 + lane;
            v[k] = (t < Tt) ? x[t] * SCALING : -1e30f;
            mx = fmaxf(mx, v[k]);
        }
        for (int off = 32; off >= 1; off >>= 1) mx = fmaxf(mx, __shfl_xor(mx, off));
        float s = 0.f;
#pragma unroll
        for (int k = 0; k < 16; ++k) {
            int t = k * 64 + lane;
            v[k] = (t < Tt) ? __expf(v[k] - mx) : 0.f;
            s += v[k];
        }
        for (int off = 32; off >= 1; off >>= 1) s += __shfl_xor(s, off);
        float inv = 1.0f / s;
        float* wrow = wout + (size_t)(wv_ * Bb + b) * Tt;
#pragma unroll
        for (int k = 0; k < 16; ++k) {
            int t = k * 64 + lane;
            if (t < Tt) {
                float ww_ = v[k] * inv;
                wl[wv_][t] = ww_;
                if (dch == 0) wrow[t] = ww_;
            }
        }
    }
    __syncthreads();

    // ---- ctx slice: ctxs[h][dd] = sum_t wl[h][t] * enc16[b][t][d0+dd] ----
    int g = tid >> 5, c = tid & 31;
    int d0 = dch * 128;
    float4 a[4];
#pragma unroll
    for (int h = 0; h < 4; ++h) a[h] = make_float4(0.f, 0.f, 0.f, 0.f);
    const unsigned short* encB = enc16 + (size_t)b * TP * EPROJS_ + d0 + c * 4;
    for (int t = g; t < Tt; t += 8) {
        uint2 raw = *(const uint2*)(encB + (size_t)t * EPROJS_);
        float x0 = __uint_as_float(raw.x << 16);
        float x1 = __uint_as_float(raw.x & 0xffff0000u);
        float x2 = __uint_as_float(raw.y << 16);
        float x3 = __uint_as_float(raw.y & 0xffff0000u);
#pragma unroll
        for (int h = 0; h < 4; ++h) {
            float wv_ = wl[h][t];
            a[h].x += wv_ * x0; a[h].y += wv_ * x1;
            a[h].z += wv_ * x2; a[h].w += wv_ * x3;
        }
    }
#pragma unroll
    for (int h = 0; h < 4; ++h)
        *(float4*)&red[((g * 4 + h) << 7) + c * 4] = a[h];
    __syncthreads();
    for (int i = tid; i < 512; i += 256) {
        int h = i >> 7, dd = i & 127;
        float ssum = 0.f;
#pragma unroll
        for (int g2 = 0; g2 < 8; ++g2) ssum += red[((g2 * 4 + h) << 7) + dd];
        ctxs[h][dd] = ssum;
    }
    __syncthreads();

    // ---- c partial: c[h,b,e] += ctxs[h,:] . Wv[h, d0:d0+128, e] ----
#pragma unroll
    for (int h = 0; h < 4; ++h) {
        const float* wvp = Wv + ((size_t)(h * EPROJS_ + d0)) * DVd;
        float a0 = 0.f, a1 = 0.f;
        for (int dl = 0; dl < 128; ++dl) {
            float cv = ctxs[h][dl];
            a0 += cv * wvp[(size_t)dl * DVd + tid];
            a1 += cv * wvp[(size_t)dl * DVd + tid + 256];
        }
        atomicAdd(&c_buf[(h * Bb + b) * DVd + tid], a0);
        atomicAdd(&c_buf[(h * Bb + b) * DVd + tid + 256], a1);
    }
}

// ---------------- out[b,o] += c[b,k0:k0+64] . Wo[k0:k0+64,o] ------------------
__global__ __launch_bounds__(256) void out_kernel(
    const float* __restrict__ c_buf, const float* __restrict__ Wo,
    float* __restrict__ outp)
{
    int ot = blockIdx.x;  // 0..7 : 128-o tile
    int kc = blockIdx.y;  // 0..31: 64-k chunk
    int k0 = kc * 64, o0 = ot * 128;
    __shared__ float cs[32][64];
    int tid = threadIdx.x;
    {
        int b = tid >> 3, k8 = (tid & 7) * 8;
        int h = k0 >> 9;
        const float* p = c_buf + ((size_t)(h * Bb + b)) * DVd + (k0 & 511) + k8;
        *(float4*)&cs[b][k8] = *(const float4*)p;
        *(float4*)&cs[b][k8 + 4] = *(const float4*)(p + 4);
    }
    __syncthreads();
    int o = o0 + (tid & 127);
    int kl0 = (tid >> 7) * 32;
    float wo[32];
#pragma unroll
    for (int kl = 0; kl < 32; ++kl)
        wo[kl] = Wo[((size_t)(k0 + kl0 + kl)) * EPROJS_ + o];
#pragma unroll
    for (int b = 0; b < 32; ++b) {
        float s = 0.f;
#pragma unroll
        for (int kl = 0; kl < 32; ++kl) s += cs[b][kl0 + kl] * wo[kl];
        atomicAdd(&outp[b * EPROJS_ + o], s);
    }
}

extern "C" void kernel_launch(void* const* d_in, const int* in_sizes, int n_in,
                              void* d_out, int out_size, void* d_ws, size_t ws_size,
                              hipStream_t stream) {
    const float* enc     = (const float*)d_in[0];
    const float* dec_z   = (const float*)d_in[2];
    const float* att_prev= (const float*)d_in[3];
    const float* Wq      = (const float*)d_in[4];
    const float* bq      = (const float*)d_in[5];
    const float* Wk      = (const float*)d_in[6];
    const float* Wv      = (const float*)d_in[7];
    const float* g_w     = (const float*)d_in[8];
    const float* Watt    = (const float*)d_in[10];
    const float* Wo      = (const float*)d_in[11];
    const float* cw0     = (const float*)d_in[12];
    const float* cw1     = (const float*)d_in[13];
    const float* cw2     = (const float*)d_in[14];
    const float* cw3     = (const float*)d_in[15];

    float* ws     = (float*)d_ws;
    float* q_part = ws;                         // 8*65536 = 524288 f (fully written)
    float* e_buf  = ws + 524288;                // 128000 f (atomics, zeroed)
    float* c_buf  = ws + 652288;                // 65536 f (atomics, zeroed)
    unsigned short* enc16 = (unsigned short*)(ws + 717824);   // 33,554,432 sh
    unsigned short* Wkt   = (unsigned short*)(ws + 17495040); // 2,097,152 sh
    __hip_bfloat16* WWt   = (__hip_bfloat16*)(ws + 18543616); // 524,288 sh
    unsigned short* att2  = (unsigned short*)(ws + 18805760); // 20,971,520 sh
    float* outp  = (float*)d_out;               // 32768 f (atomics, zeroed)
    float* wout  = outp + 32768;                // 128000 f (fully written)

    hipMemsetAsync(e_buf, 0, (size_t)193536 * sizeof(float), stream);  // e_buf+c_buf
    hipMemsetAsync(d_out, 0, (size_t)32768 * sizeof(float), stream);

    prep_kernel<<<4672, 256, 0, stream>>>(enc, Wk, cw0, cw1, cw2, cw3, Watt,
                                          att_prev, dec_z, Wq,
                                          enc16, Wkt, WWt, att2, q_part);
    e_kernel<<<4096, 256, 0, stream>>>(enc16, Wkt, att2, WWt,
                                       q_part, bq, g_w, e_buf);
    smax_ctx_c_kernel<<<dim3(8, 32), 256, 0, stream>>>(e_buf, enc16, Wv,
                                                       wout, c_buf);
    out_kernel<<<dim3(8, 32), 256, 0, stream>>>(c_buf, Wo, outp);
}